// Round 8
// baseline (246.187 us; speedup 1.0000x reference)
//
#include <hip/hip_runtime.h>

#define NBINS 1001
#define HIST_BLOCK 256
#define VPT 8                                     // float4s of x (and of y) per thread
#define ELEMS_PER_BLOCK (HIST_BLOCK * VPT * 4)    // 8192 -> 2048 blocks

typedef float fvec4 __attribute__((ext_vector_type(4)));   // clang vector: ok for nontemporal builtins

__device__ __forceinline__ int bin_of(float v) {
    // idx = #{ j in [0,999] : fp32(j/999) < v } ~= clamp(ceil(999*v), 0, 1000)
    // fp32 rounding flips a bin only when 999*v is within ~6e-5 of an integer
    // (~1e3 of 16.7M elems); each flip moves F1 by ~1e-6 << 1.08e-2 tolerance.
    int k = (int)ceilf(v * 999.0f);
    k = (k < 0) ? 0 : k;
    k = (k > 1000) ? 1000 : k;
    return k;
}

// Fused: R7 hist structure (preload-all nontemporal -> LDS atomic scatter ->
// flush) + last-block-done F1 epilogue. The DS-atomic issue rate (~1.5
// cyc/lane-op, invariant across R1-R7 variants) is the hist floor at one
// atomic per element; fusing removes the f1 dispatch + gap.
__global__ __launch_bounds__(HIST_BLOCK) void fused_kernel(
    const float* __restrict__ x, const float* __restrict__ y,
    unsigned long long* __restrict__ ghist,     // [4][NBINS] zeroed
    unsigned int* __restrict__ done_counter,    // zeroed
    float* __restrict__ out, int HW)
{
    __shared__ unsigned int lh[NBINS];
    __shared__ unsigned long long wsum[4];
    __shared__ float wmaxs[4];
    __shared__ int is_last;
    const int tid  = threadIdx.x;
    const int lane = tid & 63;
    const int wave = tid >> 6;

    const long long start = (long long)blockIdx.x * ELEMS_PER_BLOCK;
    const int c = (int)((start / HW) & 3);   // 8192 | HW=262144: block is class-uniform

    const fvec4* __restrict__ x4 = (const fvec4*)(x + start);
    const fvec4* __restrict__ y4 = (const fvec4*)(y + start);

    // ---- Phase 1: issue the whole memory phase first (single-use -> nontemporal)
    fvec4 xv[VPT], yv[VPT];
    #pragma unroll
    for (int k = 0; k < VPT; ++k) {
        const int idx = k * HIST_BLOCK + tid;    // lanes contiguous: coalesced
        xv[k] = __builtin_nontemporal_load(&x4[idx]);
        yv[k] = __builtin_nontemporal_load(&y4[idx]);
    }

    // LDS init + barrier overlap the in-flight loads.
    for (int i = tid; i < NBINS; i += HIST_BLOCK) lh[i] = 0u;
    __syncthreads();

    // ---- Phase 2: scatter. Packed u32: low16 = count, high16 = positive count
    // (block sees 8192 elems -> no overflow).
    #pragma unroll
    for (int k = 0; k < VPT; ++k) {
        // y is exactly 0.0f or 1.0f: bits(1.0f)=0x3f800000 -> (>>8)&0x10000
        atomicAdd(&lh[bin_of(xv[k].x)], 1u + ((__float_as_uint(yv[k].x) >> 8) & 0x10000u));
        atomicAdd(&lh[bin_of(xv[k].y)], 1u + ((__float_as_uint(yv[k].y) >> 8) & 0x10000u));
        atomicAdd(&lh[bin_of(xv[k].z)], 1u + ((__float_as_uint(yv[k].z) >> 8) & 0x10000u));
        atomicAdd(&lh[bin_of(xv[k].w)], 1u + ((__float_as_uint(yv[k].w) >> 8) & 0x10000u));
    }
    __syncthreads();

    // ---- Phase 3: flush to device-scope histogram (u64: low32=cnt, high32=pos)
    for (int i = tid; i < NBINS; i += HIST_BLOCK) {
        unsigned int v = lh[i];
        if (v) {
            unsigned long long add = (unsigned long long)(v & 0xffffu)
                                   | ((unsigned long long)(v >> 16) << 32);
            atomicAdd(&ghist[(size_t)c * NBINS + i], add);
        }
    }
    // __syncthreads drains vmcnt (compiler emits s_waitcnt vmcnt(0) before
    // s_barrier) -> all flush atomics are at the coherent point before tid 0
    // bumps the counter.
    __syncthreads();
    if (tid == 0) {
        __threadfence();
        unsigned int prev = atomicAdd(done_counter, 1u);
        is_last = (prev == (unsigned int)(gridDim.x - 1)) ? 1 : 0;
    }
    __syncthreads();
    if (!is_last) return;

    // ---- Phase 4 (one block only): F1 over 1000 thresholds x 4 classes.
    __threadfence();   // acquire side
    float loss = 0.0f;  // only tid 0's copy is used
    for (int cc = 0; cc < 4; ++cc) {
        // thread t owns bins [4t, 4t+3]
        const int base = tid * 4;
        unsigned long long loc[4];
        #pragma unroll
        for (int j = 0; j < 4; ++j) {
            const int i = base + j;
            loc[j] = (i < NBINS)
                ? __hip_atomic_load(&ghist[(size_t)cc * NBINS + i],
                                    __ATOMIC_RELAXED, __HIP_MEMORY_SCOPE_AGENT)
                : 0ULL;
        }
        // thread-local inclusive prefix (packed fields independent: low32 sums
        // max 4.2M < 2^32, no cross-field carry)
        #pragma unroll
        for (int j = 1; j < 4; ++j) loc[j] += loc[j - 1];
        const unsigned long long tsum = loc[3];

        // wave inclusive scan of per-thread sums
        unsigned long long incl = tsum;
        #pragma unroll
        for (int off = 1; off < 64; off <<= 1) {
            unsigned long long t = __shfl_up(incl, off, 64);
            if (lane >= off) incl += t;
        }
        const unsigned long long texcl = incl - tsum;
        if (lane == 63) wsum[wave] = incl;
        __syncthreads();

        unsigned long long wexcl = 0ULL, total = 0ULL;
        #pragma unroll
        for (int w = 0; w < 4; ++w) {
            if (w < wave) wexcl += wsum[w];
            total += wsum[w];
        }
        const unsigned long long off_v = wexcl + texcl;
        const unsigned int total_cnt = (unsigned int)(total & 0xffffffffULL); // N
        const unsigned int total_y   = (unsigned int)(total >> 32);

        float fmx = 0.0f;
        #pragma unroll
        for (int j = 0; j < 4; ++j) {
            const int i = base + j;
            if (i < NBINS - 1) {   // thresholds k = 0..999
                const unsigned long long cum = loc[j] + off_v;
                const unsigned int cnt_cum = (unsigned int)(cum & 0xffffffffULL);
                const unsigned int y_cum   = (unsigned int)(cum >> 32);
                const unsigned int TP = total_y - y_cum;
                const unsigned int PP = total_cnt - cnt_cum;
                const unsigned int denom = total_y + PP; // = 2*(TP + (FN+FP)/2)
                const float f1 = (denom == 0u) ? 0.0f
                               : (2.0f * (float)TP) / (float)denom;
                fmx = fmaxf(fmx, f1);
            }
        }
        #pragma unroll
        for (int off = 32; off > 0; off >>= 1)
            fmx = fmaxf(fmx, __shfl_down(fmx, off, 64));
        if (lane == 0) wmaxs[wave] = fmx;
        __syncthreads();
        if (tid == 0) {
            float mm = fmaxf(fmaxf(wmaxs[0], wmaxs[1]), fmaxf(wmaxs[2], wmaxs[3]));
            loss += 1.0f - mm;
        }
        __syncthreads();   // protect wsum/wmaxs before next class
    }
    if (tid == 0) out[0] = loss * 0.25f;
}

extern "C" void kernel_launch(void* const* d_in, const int* in_sizes, int n_in,
                              void* d_out, int out_size, void* d_ws, size_t ws_size,
                              hipStream_t stream) {
    const float* x = (const float*)d_in[0];
    const float* y = (const float*)d_in[1];
    float* out = (float*)d_out;

    const int H = 512, W = 512;
    const int HW = H * W;
    const long long total = (long long)in_sizes[0];   // 16777216

    // d_ws layout: ghist[4*NBINS] u64, then done_counter (u64 slot)
    unsigned long long* ghist = (unsigned long long*)d_ws;
    unsigned int* done_counter = (unsigned int*)(ghist + 4 * NBINS);

    (void)hipMemsetAsync(d_ws, 0, ((size_t)4 * NBINS + 1) * sizeof(unsigned long long), stream);

    const int nblocks = (int)(total / ELEMS_PER_BLOCK);  // 2048
    fused_kernel<<<nblocks, HIST_BLOCK, 0, stream>>>(x, y, ghist, done_counter, out, HW);
    (void)n_in; (void)out_size; (void)ws_size;
}

// Round 9
// 148.897 us; speedup vs baseline: 1.6534x; 1.6534x over previous
//
#include <hip/hip_runtime.h>

#define NBINS 1001
#define HIST_BLOCK 256
#define VPT 8                                     // float4s of x (and of y) per thread
#define ELEMS_PER_BLOCK (HIST_BLOCK * VPT * 4)    // 8192 -> 2048 blocks

typedef float fvec4 __attribute__((ext_vector_type(4)));   // clang vector: ok for nontemporal builtins

__device__ __forceinline__ int bin_of(float v) {
    // idx = #{ j in [0,999] : fp32(j/999) < v } ~= clamp(ceil(999*v), 0, 1000)
    // fp32 rounding flips a bin only when 999*v is within ~6e-5 of an integer
    // (~1e3 of 16.7M elems); each flip moves F1 by ~1e-6 << 1.08e-2 tolerance.
    int k = (int)ceilf(v * 999.0f);
    k = (k < 0) ? 0 : k;
    k = (k > 1000) ? 1000 : k;
    return k;
}

// R7 structure (best: total 147.2 us). Preload ALL 16 nontemporal loads before
// the LDS init barrier (16 KB/wave in flight through the barrier), then the
// LDS atomic scatter. Scattered ds_add issue rate ~1.5 cyc/lane is the floor
// (invariant across 7 structural variants); one atomic/element is minimal.
// DO NOT fuse f1 via last-block-done: per-block __threadfence = L2 writeback
// on gfx950 -> 3x regression (R8: WRITE_SIZE 4.2->16.8 MB, 40->136 us).
__global__ __launch_bounds__(HIST_BLOCK) void hist_kernel(
    const float* __restrict__ x, const float* __restrict__ y,
    unsigned long long* __restrict__ ghist, int HW)
{
    __shared__ unsigned int lh[NBINS];
    const int tid = threadIdx.x;

    const long long start = (long long)blockIdx.x * ELEMS_PER_BLOCK;
    const int c = (int)((start / HW) & 3);   // 8192 | HW=262144: block is class-uniform

    const fvec4* __restrict__ x4 = (const fvec4*)(x + start);
    const fvec4* __restrict__ y4 = (const fvec4*)(y + start);

    // Issue the whole memory phase first (single-use data -> nontemporal).
    fvec4 xv[VPT], yv[VPT];
    #pragma unroll
    for (int k = 0; k < VPT; ++k) {
        const int idx = k * HIST_BLOCK + tid;    // lanes contiguous: coalesced
        xv[k] = __builtin_nontemporal_load(&x4[idx]);
        yv[k] = __builtin_nontemporal_load(&y4[idx]);
    }

    // LDS init + barrier overlap the in-flight loads.
    for (int i = tid; i < NBINS; i += HIST_BLOCK) lh[i] = 0u;
    __syncthreads();

    // Packed u32 bins: low16 = count, high16 = positive count (8192 elems/block
    // -> no overflow). One LDS atomic per element is the scatter minimum.
    #pragma unroll
    for (int k = 0; k < VPT; ++k) {
        // y is exactly 0.0f or 1.0f: bits(1.0f)=0x3f800000 -> (>>8)&0x10000
        atomicAdd(&lh[bin_of(xv[k].x)], 1u + ((__float_as_uint(yv[k].x) >> 8) & 0x10000u));
        atomicAdd(&lh[bin_of(xv[k].y)], 1u + ((__float_as_uint(yv[k].y) >> 8) & 0x10000u));
        atomicAdd(&lh[bin_of(xv[k].z)], 1u + ((__float_as_uint(yv[k].z) >> 8) & 0x10000u));
        atomicAdd(&lh[bin_of(xv[k].w)], 1u + ((__float_as_uint(yv[k].w) >> 8) & 0x10000u));
    }
    __syncthreads();

    // Flush: unpack u32 -> u64 (low32 = count, high32 = positive count)
    for (int i = tid; i < NBINS; i += HIST_BLOCK) {
        unsigned int v = lh[i];
        if (v) {
            unsigned long long add = (unsigned long long)(v & 0xffffu)
                                   | ((unsigned long long)(v >> 16) << 32);
            atomicAdd(&ghist[(size_t)c * NBINS + i], add);
        }
    }
}

// One block, 1024 threads; thread t owns bin t for all 4 classes.
__global__ __launch_bounds__(1024) void f1_kernel(
    const unsigned long long* __restrict__ ghist, float* __restrict__ out)
{
    __shared__ unsigned long long wtot[4][16];
    __shared__ float wmax[4][16];
    const int tid  = threadIdx.x;
    const int lane = tid & 63;
    const int wave = tid >> 6;

    unsigned long long v[4];
    #pragma unroll
    for (int c = 0; c < 4; ++c)
        v[c] = (tid < NBINS) ? ghist[(size_t)c * NBINS + tid] : 0ULL;

    // intra-wave inclusive scan (u64, packed cnt | ycnt<<32 - fields can't interact)
    #pragma unroll
    for (int off = 1; off < 64; off <<= 1) {
        #pragma unroll
        for (int c = 0; c < 4; ++c) {
            unsigned long long t = __shfl_up(v[c], off, 64);
            if (lane >= off) v[c] += t;
        }
    }
    if (lane == 63) {
        #pragma unroll
        for (int c = 0; c < 4; ++c) wtot[c][wave] = v[c];
    }
    __syncthreads();

    // wave 0: inclusive scan of the 16 wave totals per class (lane = c*16 + w)
    if (wave == 0) {
        const int c = lane >> 4, w = lane & 15;
        unsigned long long t = wtot[c][w];
        #pragma unroll
        for (int off = 1; off < 16; off <<= 1) {
            unsigned long long s = __shfl_up(t, off, 16);
            if (w >= off) t += s;
        }
        wtot[c][w] = t;
    }
    __syncthreads();

    float m[4];
    #pragma unroll
    for (int c = 0; c < 4; ++c) {
        unsigned long long cum = v[c];
        if (wave > 0) cum += wtot[c][wave - 1];
        unsigned long long tot = wtot[c][15];
        unsigned int total_cnt = (unsigned int)(tot & 0xffffffffULL);  // N per class
        unsigned int total_y   = (unsigned int)(tot >> 32);
        float f1 = 0.0f;
        if (tid < NBINS - 1) {  // thresholds k = 0..999
            unsigned int cnt_cum = (unsigned int)(cum & 0xffffffffULL);
            unsigned int y_cum   = (unsigned int)(cum >> 32);
            unsigned int TP = total_y - y_cum;
            unsigned int PP = total_cnt - cnt_cum;
            unsigned int denom = total_y + PP;  // = 2*(TP + 0.5*(FN+FP))
            f1 = (denom == 0u) ? 0.0f : (2.0f * (float)TP) / (float)denom;
        }
        m[c] = f1;
    }

    // wave max-reduce per class
    #pragma unroll
    for (int off = 32; off > 0; off >>= 1) {
        #pragma unroll
        for (int c = 0; c < 4; ++c)
            m[c] = fmaxf(m[c], __shfl_down(m[c], off, 64));
    }
    if (lane == 0) {
        #pragma unroll
        for (int c = 0; c < 4; ++c) wmax[c][wave] = m[c];
    }
    __syncthreads();

    if (tid == 0) {
        float loss = 0.0f;
        #pragma unroll
        for (int c = 0; c < 4; ++c) {
            float mm = wmax[c][0];
            #pragma unroll
            for (int w = 1; w < 16; ++w) mm = fmaxf(mm, wmax[c][w]);
            loss += 1.0f - mm;
        }
        out[0] = loss * 0.25f;
    }
}

extern "C" void kernel_launch(void* const* d_in, const int* in_sizes, int n_in,
                              void* d_out, int out_size, void* d_ws, size_t ws_size,
                              hipStream_t stream) {
    const float* x = (const float*)d_in[0];
    const float* y = (const float*)d_in[1];
    float* out = (float*)d_out;

    const int H = 512, W = 512;
    const int HW = H * W;
    const long long total = (long long)in_sizes[0];   // 16777216

    unsigned long long* ghist = (unsigned long long*)d_ws;

    (void)hipMemsetAsync(d_ws, 0, (size_t)4 * NBINS * sizeof(unsigned long long), stream);

    const int nblocks = (int)(total / ELEMS_PER_BLOCK);  // 2048
    hist_kernel<<<nblocks, HIST_BLOCK, 0, stream>>>(x, y, ghist, HW);
    f1_kernel<<<1, 1024, 0, stream>>>(ghist, out);
    (void)n_in; (void)out_size; (void)ws_size;
}